// Round 1
// baseline (61.209 us; speedup 1.0000x reference)
//
#include <hip/hip_runtime.h>
#include <stdint.h>

#define TOKENS 32768
#define IN_F   512
#define OUT_F  512
#define KW     16          // 512 bits -> 16 u32 words per row

// ---------------------------------------------------------------------------
// Kernel A: binarize weight (minus per-row threshold) into transposed
// bit-plane layout wbT[k][o], k = bit-word index 0..15, o = output feature.
// One wave per output row o; __ballot packs 64 sign bits at a time.
// ---------------------------------------------------------------------------
__global__ __launch_bounds__(256) void binw_kernel(
    const float* __restrict__ w,      // [OUT_F][IN_F]
    const float* __restrict__ thr,    // [OUT_F]
    uint32_t* __restrict__ wbT)       // [KW][OUT_F]
{
    const int gtid = blockIdx.x * blockDim.x + threadIdx.x;
    const int o    = gtid >> 6;        // wave id == output row (exactly 512 waves)
    const int lane = threadIdx.x & 63;

    const float t = thr[o];
#pragma unroll
    for (int c = 0; c < 8; ++c) {
        float v = w[o * IN_F + c * 64 + lane] - t;
        unsigned long long m = __ballot(v >= 0.0f);
        if (lane == 0) {
            wbT[(2 * c)     * OUT_F + o] = (uint32_t)m;
            wbT[(2 * c + 1) * OUT_F + o] = (uint32_t)(m >> 32);
        }
    }
}

// ---------------------------------------------------------------------------
// Kernel B: fused binarize-x + binary GEMM.
// Block = 256 threads (4 waves). Block covers 16 rows (4 rows/wave).
// wbT (32 KB) staged once per block into LDS.
// Per wave: binarize 4 rows via __ballot (wave-uniform 16 words/row), then
// for each column-group (lane owns 4 consecutive columns) loop k=0..15:
// one ds_read_b128 of wbT[k][cb..cb+3] + 16 xor + 16 bcnt-accumulate.
// ---------------------------------------------------------------------------
__global__ __launch_bounds__(256) void bgemm_kernel(
    const float*    __restrict__ x,     // [TOKENS][IN_F]
    const uint32_t* __restrict__ wbT,   // [KW][OUT_F]
    const float*    __restrict__ shift, // [1]
    float*          __restrict__ out)   // [TOKENS][OUT_F]
{
    __shared__ uint32_t lwbT[KW * OUT_F];   // 32 KB

    // stage wbT -> LDS (8192 words = 2048 uint4, 256 threads x 8 iters)
#pragma unroll
    for (int i = 0; i < 8; ++i) {
        int idx = i * 256 + threadIdx.x;
        ((uint4*)lwbT)[idx] = ((const uint4*)wbT)[idx];
    }
    __syncthreads();

    // scale = 2^round(clip(shift, -8, 0)), round-half-to-even == rintf
    float s = shift[0];
    s = fminf(fmaxf(s, -8.0f), 0.0f);
    const float scale = exp2f(rintf(s));

    const int lane = threadIdx.x & 63;
    const int wid  = threadIdx.x >> 6;
    const int row0 = blockIdx.x * 16 + wid * 4;

    // --- binarize 4 rows of x, wave-uniform bit words ---
    uint32_t xw[4][KW];
#pragma unroll
    for (int r = 0; r < 4; ++r) {
#pragma unroll
        for (int c = 0; c < 8; ++c) {
            float v = x[(row0 + r) * IN_F + c * 64 + lane];
            unsigned long long m = __ballot(v >= 0.0f);
            xw[r][2 * c]     = (uint32_t)m;
            xw[r][2 * c + 1] = (uint32_t)(m >> 32);
        }
    }

    // --- two column groups of 256; lane owns 4 consecutive columns ---
#pragma unroll
    for (int og = 0; og < 2; ++og) {
        const int cb = og * 256 + lane * 4;

        uint32_t acc[4][4];
#pragma unroll
        for (int r = 0; r < 4; ++r) {
            acc[r][0] = 0; acc[r][1] = 0; acc[r][2] = 0; acc[r][3] = 0;
        }

#pragma unroll
        for (int k = 0; k < KW; ++k) {
            uint4 wv = *(const uint4*)&lwbT[k * OUT_F + cb];
#pragma unroll
            for (int r = 0; r < 4; ++r) {
                uint32_t xk = xw[r][k];
                acc[r][0] += __popc(xk ^ wv.x);
                acc[r][1] += __popc(xk ^ wv.y);
                acc[r][2] += __popc(xk ^ wv.z);
                acc[r][3] += __popc(xk ^ wv.w);
            }
        }

#pragma unroll
        for (int r = 0; r < 4; ++r) {
            float4 o4;
            o4.x = (float)(IN_F - 2 * (int)acc[r][0]) * scale;
            o4.y = (float)(IN_F - 2 * (int)acc[r][1]) * scale;
            o4.z = (float)(IN_F - 2 * (int)acc[r][2]) * scale;
            o4.w = (float)(IN_F - 2 * (int)acc[r][3]) * scale;
            *(float4*)&out[(row0 + r) * OUT_F + cb] = o4;
        }
    }
}

extern "C" void kernel_launch(void* const* d_in, const int* in_sizes, int n_in,
                              void* d_out, int out_size, void* d_ws, size_t ws_size,
                              hipStream_t stream) {
    const float* x     = (const float*)d_in[0];
    const float* w     = (const float*)d_in[1];
    const float* thr   = (const float*)d_in[2];
    const float* shift = (const float*)d_in[3];
    float*       out   = (float*)d_out;
    uint32_t*    wbT   = (uint32_t*)d_ws;   // 16*512*4 = 32 KB scratch

    // 512 waves exactly: 128 blocks x 4 waves
    binw_kernel<<<128, 256, 0, stream>>>(w, thr, wbT);
    // 32768 rows / 16 rows per block = 2048 blocks
    bgemm_kernel<<<2048, 256, 0, stream>>>(x, wbT, shift, out);
}

// Round 2
// 56.528 us; speedup vs baseline: 1.0828x; 1.0828x over previous
//
#include <hip/hip_runtime.h>
#include <stdint.h>

#define TOKENS 32768
#define IN_F   512
#define OUT_F  512
#define KW     16          // 512 bits -> 16 u32 words per row

// ---------------------------------------------------------------------------
// Bit-packing permutation (identical in kernels A and B, so XOR+popc dot
// products are unaffected): word k = j*8 + c*2 + h holds, in bit position l
// (h=0: lanes 0..31, h=1: lanes 32..63), the sign of element j*256 + 4*l + c.
// This lets both kernels use float4 (16 B/lane) loads.
// ---------------------------------------------------------------------------

// Kernel A: binarize weight (minus per-row threshold) into transposed
// bit-plane layout wbT[k][o]. One wave per output row o.
__global__ __launch_bounds__(256) void binw_kernel(
    const float* __restrict__ w,      // [OUT_F][IN_F]
    const float* __restrict__ thr,    // [OUT_F]
    uint32_t* __restrict__ wbT)       // [KW][OUT_F]
{
    const int o    = (blockIdx.x * 256 + threadIdx.x) >> 6;  // 512 waves total
    const int lane = threadIdx.x & 63;

    const float t = thr[o];
    const float4* wr = (const float4*)(w + (size_t)o * IN_F);
#pragma unroll
    for (int j = 0; j < 2; ++j) {
        float4 v = wr[j * 64 + lane];
        float vals[4] = {v.x - t, v.y - t, v.z - t, v.w - t};
#pragma unroll
        for (int c = 0; c < 4; ++c) {
            unsigned long long m = __ballot(vals[c] >= 0.0f);
            if (lane == 0) {
                wbT[(j * 8 + c * 2 + 0) * OUT_F + o] = (uint32_t)m;
                wbT[(j * 8 + c * 2 + 1) * OUT_F + o] = (uint32_t)(m >> 32);
            }
        }
    }
}

// Kernel B: fused binarize-x + binary GEMM.
// Block = 512 threads (8 waves), 2 rows per wave -> 16 rows/block.
// __launch_bounds__(512, 8): target 8 waves/SIMD = 4 blocks/CU (128 KB LDS).
__global__ __launch_bounds__(512, 8) void bgemm_kernel(
    const float*    __restrict__ x,     // [TOKENS][IN_F]
    const uint32_t* __restrict__ wbT,   // [KW][OUT_F]
    const float*    __restrict__ shift, // [1]
    float*          __restrict__ out)   // [TOKENS][OUT_F]
{
    __shared__ uint32_t lwbT[KW * OUT_F];   // 32 KB

    const int lane = threadIdx.x & 63;
    const int wid  = threadIdx.x >> 6;          // 0..7
    const int row0 = blockIdx.x * 16 + wid * 2;

    // --- issue x loads first so HBM latency hides under LDS staging ---
    const float4* xr = (const float4*)x;
    float4 xa[2][2];
#pragma unroll
    for (int r = 0; r < 2; ++r)
#pragma unroll
        for (int j = 0; j < 2; ++j)
            xa[r][j] = xr[(size_t)(row0 + r) * 128 + j * 64 + lane];

    // --- stage wbT -> LDS (2048 uint4 / 512 threads = 4 each) ---
#pragma unroll
    for (int i = 0; i < 4; ++i) {
        int idx = i * 512 + threadIdx.x;
        ((uint4*)lwbT)[idx] = ((const uint4*)wbT)[idx];
    }
    __syncthreads();

    // scale = 2^round(clip(shift, -8, 0)), round-half-even == rintf
    float s = shift[0];
    s = fminf(fmaxf(s, -8.0f), 0.0f);
    const float scale = exp2f(rintf(s));

    // --- binarize 2 rows (permuted packing, wave-uniform words) ---
    uint32_t xw[2][KW];
#pragma unroll
    for (int r = 0; r < 2; ++r)
#pragma unroll
        for (int j = 0; j < 2; ++j) {
            float4 v = xa[r][j];
            unsigned long long m;
            m = __ballot(v.x >= 0.0f);
            xw[r][j * 8 + 0] = (uint32_t)m; xw[r][j * 8 + 1] = (uint32_t)(m >> 32);
            m = __ballot(v.y >= 0.0f);
            xw[r][j * 8 + 2] = (uint32_t)m; xw[r][j * 8 + 3] = (uint32_t)(m >> 32);
            m = __ballot(v.z >= 0.0f);
            xw[r][j * 8 + 4] = (uint32_t)m; xw[r][j * 8 + 5] = (uint32_t)(m >> 32);
            m = __ballot(v.w >= 0.0f);
            xw[r][j * 8 + 6] = (uint32_t)m; xw[r][j * 8 + 7] = (uint32_t)(m >> 32);
        }

    // --- two column groups of 256; lane owns 4 consecutive columns ---
#pragma unroll
    for (int og = 0; og < 2; ++og) {
        const int cb = og * 256 + lane * 4;

        uint32_t acc[2][4];
#pragma unroll
        for (int r = 0; r < 2; ++r) {
            acc[r][0] = 0; acc[r][1] = 0; acc[r][2] = 0; acc[r][3] = 0;
        }

#pragma unroll
        for (int k = 0; k < KW; ++k) {
            uint4 wv = *(const uint4*)&lwbT[k * OUT_F + cb];
#pragma unroll
            for (int r = 0; r < 2; ++r) {
                uint32_t xk = xw[r][k];
                acc[r][0] += __popc(xk ^ wv.x);
                acc[r][1] += __popc(xk ^ wv.y);
                acc[r][2] += __popc(xk ^ wv.z);
                acc[r][3] += __popc(xk ^ wv.w);
            }
        }

#pragma unroll
        for (int r = 0; r < 2; ++r) {
            float4 o4;
            o4.x = (float)(IN_F - 2 * (int)acc[r][0]) * scale;
            o4.y = (float)(IN_F - 2 * (int)acc[r][1]) * scale;
            o4.z = (float)(IN_F - 2 * (int)acc[r][2]) * scale;
            o4.w = (float)(IN_F - 2 * (int)acc[r][3]) * scale;
            *(float4*)&out[(size_t)(row0 + r) * OUT_F + cb] = o4;
        }
    }
}

extern "C" void kernel_launch(void* const* d_in, const int* in_sizes, int n_in,
                              void* d_out, int out_size, void* d_ws, size_t ws_size,
                              hipStream_t stream) {
    const float* x     = (const float*)d_in[0];
    const float* w     = (const float*)d_in[1];
    const float* thr   = (const float*)d_in[2];
    const float* shift = (const float*)d_in[3];
    float*       out   = (float*)d_out;
    uint32_t*    wbT   = (uint32_t*)d_ws;   // 16*512*4 = 32 KB scratch

    binw_kernel<<<128, 256, 0, stream>>>(w, thr, wbT);
    bgemm_kernel<<<TOKENS / 16, 512, 0, stream>>>(x, wbT, shift, out);
}

// Round 3
// 36.014 us; speedup vs baseline: 1.6996x; 1.5696x over previous
//
#include <hip/hip_runtime.h>
#include <stdint.h>

#define TOKENS 32768
#define IN_F   512
#define OUT_F  512
#define KW     16          // 512 bits -> 16 u32 words per row

// ---------------------------------------------------------------------------
// Bit-packing permutation (identical in both kernels, so XOR+popc dot
// products are unaffected): from a row read as float4[128] (index f, lane l),
// word k = f_hi*8 + c*2 + h holds in bit l the sign of float4 #(f_hi*64+l)
// element c (h selects lanes 0..31 / 32..63).
// ---------------------------------------------------------------------------

// Kernel A: binarize weight (minus per-row threshold) into transposed
// bit-plane layout wbT[k][o]. One wave per output row o.
__global__ __launch_bounds__(256) void binw_kernel(
    const float* __restrict__ w,      // [OUT_F][IN_F]
    const float* __restrict__ thr,    // [OUT_F]
    uint32_t* __restrict__ wbT)       // [KW][OUT_F]
{
    const int o    = (blockIdx.x * 256 + threadIdx.x) >> 6;  // 512 waves total
    const int lane = threadIdx.x & 63;

    const float t = thr[o];
    const float4* wr = (const float4*)(w + (size_t)o * IN_F);
#pragma unroll
    for (int j = 0; j < 2; ++j) {
        float4 v = wr[j * 64 + lane];
        float vals[4] = {v.x - t, v.y - t, v.z - t, v.w - t};
#pragma unroll
        for (int c = 0; c < 4; ++c) {
            unsigned long long m = __ballot(vals[c] >= 0.0f);
            if (lane == 0) {
                wbT[(j * 8 + c * 2 + 0) * OUT_F + o] = (uint32_t)m;
                wbT[(j * 8 + c * 2 + 1) * OUT_F + o] = (uint32_t)(m >> 32);
            }
        }
    }
}

// ---------------------------------------------------------------------------
// Kernel B: fused binarize-x + binary GEMM, weight bits resident in VGPRs.
// No LDS, no barriers. 4096 waves; wave gw owns og = gw&1 (256 columns,
// lane -> 4 consecutive cols) and rows row_base + j*2048, j=0..15.
// Depth-1 prefetch of the next x row hides HBM latency.
// ---------------------------------------------------------------------------
__global__ __launch_bounds__(256, 4) void bgemm_kernel(
    const float*    __restrict__ x,     // [TOKENS][IN_F]
    const uint32_t* __restrict__ wbT,   // [KW][OUT_F]
    const float*    __restrict__ shift, // [1]
    float*          __restrict__ out)   // [TOKENS][OUT_F]
{
    const int lane = threadIdx.x & 63;
    const int wid  = threadIdx.x >> 6;
    const int gw   = blockIdx.x * 4 + wid;      // 0..4095
    const int og   = gw & 1;
    const int row_base = gw >> 1;               // 0..2047

    // --- weight bits for this wave's 256 columns: 64 VGPRs, loaded once ---
    uint32_t wv[KW][4];
    const uint32_t* wp = wbT + og * 256 + lane * 4;
#pragma unroll
    for (int k = 0; k < KW; ++k) {
        uint4 v = *(const uint4*)(wp + k * OUT_F);
        wv[k][0] = v.x; wv[k][1] = v.y; wv[k][2] = v.z; wv[k][3] = v.w;
    }

    // scale = 2^round(clip(shift, -8, 0)), round-half-even == rintf
    float s = shift[0];
    s = fminf(fmaxf(s, -8.0f), 0.0f);
    const float scale   = exp2f(rintf(s));
    const float negtwos = -2.0f * scale;
    const float basev   = (float)IN_F * scale;

    const float4* xr = (const float4*)x;

    float4 xa0 = xr[(size_t)row_base * 128 + lane];
    float4 xa1 = xr[(size_t)row_base * 128 + 64 + lane];

    for (int j = 0; j < 16; ++j) {
        const int row = row_base + j * 2048;

        // prefetch next row (uniform branch; last iter reuses current regs)
        float4 xb0 = xa0, xb1 = xa1;
        if (j < 15) {
            const size_t nb = (size_t)(row + 2048) * 128;
            xb0 = xr[nb + lane];
            xb1 = xr[nb + 64 + lane];
        }

        // ballot-pack current row: 8 lane-values -> 16 wave-uniform words
        uint32_t xw[KW];
        {
            unsigned long long m;
            m = __ballot(xa0.x >= 0.0f); xw[0]  = (uint32_t)m; xw[1]  = (uint32_t)(m >> 32);
            m = __ballot(xa0.y >= 0.0f); xw[2]  = (uint32_t)m; xw[3]  = (uint32_t)(m >> 32);
            m = __ballot(xa0.z >= 0.0f); xw[4]  = (uint32_t)m; xw[5]  = (uint32_t)(m >> 32);
            m = __ballot(xa0.w >= 0.0f); xw[6]  = (uint32_t)m; xw[7]  = (uint32_t)(m >> 32);
            m = __ballot(xa1.x >= 0.0f); xw[8]  = (uint32_t)m; xw[9]  = (uint32_t)(m >> 32);
            m = __ballot(xa1.y >= 0.0f); xw[10] = (uint32_t)m; xw[11] = (uint32_t)(m >> 32);
            m = __ballot(xa1.z >= 0.0f); xw[12] = (uint32_t)m; xw[13] = (uint32_t)(m >> 32);
            m = __ballot(xa1.w >= 0.0f); xw[14] = (uint32_t)m; xw[15] = (uint32_t)(m >> 32);
        }

        uint32_t acc0 = 0, acc1 = 0, acc2 = 0, acc3 = 0;
#pragma unroll
        for (int k = 0; k < KW; ++k) {
            acc0 += __popc(xw[k] ^ wv[k][0]);
            acc1 += __popc(xw[k] ^ wv[k][1]);
            acc2 += __popc(xw[k] ^ wv[k][2]);
            acc3 += __popc(xw[k] ^ wv[k][3]);
        }

        // (512 - 2*acc) * scale, exact in fp32
        float4 o4;
        o4.x = fmaf(negtwos, (float)acc0, basev);
        o4.y = fmaf(negtwos, (float)acc1, basev);
        o4.z = fmaf(negtwos, (float)acc2, basev);
        o4.w = fmaf(negtwos, (float)acc3, basev);
        *(float4*)&out[(size_t)row * OUT_F + og * 256 + lane * 4] = o4;

        xa0 = xb0; xa1 = xb1;
    }
}

extern "C" void kernel_launch(void* const* d_in, const int* in_sizes, int n_in,
                              void* d_out, int out_size, void* d_ws, size_t ws_size,
                              hipStream_t stream) {
    const float* x     = (const float*)d_in[0];
    const float* w     = (const float*)d_in[1];
    const float* thr   = (const float*)d_in[2];
    const float* shift = (const float*)d_in[3];
    float*       out   = (float*)d_out;
    uint32_t*    wbT   = (uint32_t*)d_ws;   // 16*512*4 = 32 KB scratch

    binw_kernel<<<128, 256, 0, stream>>>(w, thr, wbT);
    bgemm_kernel<<<1024, 256, 0, stream>>>(x, wbT, shift, out);
}

// Round 4
// 33.135 us; speedup vs baseline: 1.8472x; 1.0869x over previous
//
#include <hip/hip_runtime.h>
#include <stdint.h>

#define TOKENS 32768
#define IN_F   512
#define OUT_F  512
#define KW     16          // 512 bits -> 16 u32 words per row

typedef float f32x4 __attribute__((ext_vector_type(4)));

// ---------------------------------------------------------------------------
// Bit-packing permutation (identical in both kernels, so XOR+popc dot
// products are unaffected): from a row read as float4[128] (index f, lane l),
// word k = f_hi*8 + c*2 + h holds in bit l the sign of float4 #(f_hi*64+l)
// element c (h selects lanes 0..31 / 32..63).
// ---------------------------------------------------------------------------

// Kernel A: binarize weight (minus per-row threshold) into transposed
// bit-plane layout wbT[k][o]. One wave per output row o.
__global__ __launch_bounds__(256) void binw_kernel(
    const float* __restrict__ w,      // [OUT_F][IN_F]
    const float* __restrict__ thr,    // [OUT_F]
    uint32_t* __restrict__ wbT)       // [KW][OUT_F]
{
    const int o    = (blockIdx.x * 256 + threadIdx.x) >> 6;  // 512 waves total
    const int lane = threadIdx.x & 63;

    const float t = thr[o];
    const float4* wr = (const float4*)(w + (size_t)o * IN_F);
#pragma unroll
    for (int j = 0; j < 2; ++j) {
        float4 v = wr[j * 64 + lane];
        float vals[4] = {v.x - t, v.y - t, v.z - t, v.w - t};
#pragma unroll
        for (int c = 0; c < 4; ++c) {
            unsigned long long m = __ballot(vals[c] >= 0.0f);
            if (lane == 0) {
                wbT[(j * 8 + c * 2 + 0) * OUT_F + o] = (uint32_t)m;
                wbT[(j * 8 + c * 2 + 1) * OUT_F + o] = (uint32_t)(m >> 32);
            }
        }
    }
}

// ---------------------------------------------------------------------------
// Kernel B: fused binarize-x + binary GEMM, weight bits resident in VGPRs.
// No LDS, no barriers. Wave gw owns og = gw&1 (256 cols, lane -> 4 cols)
// and rows row_base + j*2048, j=0..15. Depth-2 prefetch: pack row j into
// SGPR words (freeing its register slot), then issue the row j+2 load into
// that slot -> ~2 full iterations of latency cover. Non-temporal stores
// keep L2 for the x stream.
// ---------------------------------------------------------------------------
__global__ __launch_bounds__(256, 4) void bgemm_kernel(
    const float*    __restrict__ x,     // [TOKENS][IN_F]
    const uint32_t* __restrict__ wbT,   // [KW][OUT_F]
    const float*    __restrict__ shift, // [1]
    float*          __restrict__ out)   // [TOKENS][OUT_F]
{
    const int lane = threadIdx.x & 63;
    const int wid  = threadIdx.x >> 6;
    const int gw   = blockIdx.x * 4 + wid;      // 0..4095
    const int og   = gw & 1;
    const int row_base = gw >> 1;               // 0..2047

    // --- weight bits for this wave's 256 columns: 64 VGPRs, loaded once ---
    uint32_t wv[KW][4];
    const uint32_t* wp = wbT + og * 256 + lane * 4;
#pragma unroll
    for (int k = 0; k < KW; ++k) {
        uint4 v = *(const uint4*)(wp + k * OUT_F);
        wv[k][0] = v.x; wv[k][1] = v.y; wv[k][2] = v.z; wv[k][3] = v.w;
    }

    // scale = 2^round(clip(shift, -8, 0)), round-half-even == rintf
    float s = shift[0];
    s = fminf(fmaxf(s, -8.0f), 0.0f);
    const float scale   = exp2f(rintf(s));
    const float negtwos = -2.0f * scale;
    const float basev   = (float)IN_F * scale;

    const float4* xr = (const float4*)x;

    // two row slots in flight
    float4 a[2][2];
    a[0][0] = xr[(size_t)row_base * 128 + lane];
    a[0][1] = xr[(size_t)row_base * 128 + 64 + lane];
    a[1][0] = xr[(size_t)(row_base + 2048) * 128 + lane];
    a[1][1] = xr[(size_t)(row_base + 2048) * 128 + 64 + lane];

#pragma unroll
    for (int j = 0; j < 16; ++j) {
        const int slot = j & 1;
        const int row  = row_base + j * 2048;

        // 1) ballot-pack row j -> wave-uniform words (frees slot's VGPRs)
        uint32_t xw[KW];
        {
            unsigned long long m;
            m = __ballot(a[slot][0].x >= 0.0f); xw[0]  = (uint32_t)m; xw[1]  = (uint32_t)(m >> 32);
            m = __ballot(a[slot][0].y >= 0.0f); xw[2]  = (uint32_t)m; xw[3]  = (uint32_t)(m >> 32);
            m = __ballot(a[slot][0].z >= 0.0f); xw[4]  = (uint32_t)m; xw[5]  = (uint32_t)(m >> 32);
            m = __ballot(a[slot][0].w >= 0.0f); xw[6]  = (uint32_t)m; xw[7]  = (uint32_t)(m >> 32);
            m = __ballot(a[slot][1].x >= 0.0f); xw[8]  = (uint32_t)m; xw[9]  = (uint32_t)(m >> 32);
            m = __ballot(a[slot][1].y >= 0.0f); xw[10] = (uint32_t)m; xw[11] = (uint32_t)(m >> 32);
            m = __ballot(a[slot][1].z >= 0.0f); xw[12] = (uint32_t)m; xw[13] = (uint32_t)(m >> 32);
            m = __ballot(a[slot][1].w >= 0.0f); xw[14] = (uint32_t)m; xw[15] = (uint32_t)(m >> 32);
        }

        // 2) issue depth-2 prefetch of row j+2 into the freed slot
        if (j < 14) {
            const size_t nb = (size_t)(row + 4096) * 128;
            a[slot][0] = xr[nb + lane];
            a[slot][1] = xr[nb + 64 + lane];
        }

        // 3) XOR + popcount accumulate (wave-uniform xw vs per-lane wv)
        uint32_t acc0 = 0, acc1 = 0, acc2 = 0, acc3 = 0;
#pragma unroll
        for (int k = 0; k < KW; ++k) {
            acc0 += __popc(xw[k] ^ wv[k][0]);
            acc1 += __popc(xw[k] ^ wv[k][1]);
            acc2 += __popc(xw[k] ^ wv[k][2]);
            acc3 += __popc(xw[k] ^ wv[k][3]);
        }

        // 4) (512 - 2*acc) * scale, exact in fp32; non-temporal store
        f32x4 o4;
        o4.x = fmaf(negtwos, (float)acc0, basev);
        o4.y = fmaf(negtwos, (float)acc1, basev);
        o4.z = fmaf(negtwos, (float)acc2, basev);
        o4.w = fmaf(negtwos, (float)acc3, basev);
        __builtin_nontemporal_store(o4,
            (f32x4*)&out[(size_t)row * OUT_F + og * 256 + lane * 4]);
    }
}

extern "C" void kernel_launch(void* const* d_in, const int* in_sizes, int n_in,
                              void* d_out, int out_size, void* d_ws, size_t ws_size,
                              hipStream_t stream) {
    const float* x     = (const float*)d_in[0];
    const float* w     = (const float*)d_in[1];
    const float* thr   = (const float*)d_in[2];
    const float* shift = (const float*)d_in[3];
    float*       out   = (float*)d_out;
    uint32_t*    wbT   = (uint32_t*)d_ws;   // 16*512*4 = 32 KB scratch

    binw_kernel<<<128, 256, 0, stream>>>(w, thr, wbT);
    bgemm_kernel<<<1024, 256, 0, stream>>>(x, wbT, shift, out);
}